// Round 10
// baseline (185.356 us; speedup 1.0000x reference)
//
#include <hip/hip_runtime.h>

// 2-layer fused LSTM + linear head.  B=8192, T=128, D=32, H=64, gates=256.
// R10 = R9 + forced ANTI-PHASE of the 2 co-resident blocks/CU: odd blocks
// spin ~1700cy (dependent rcp chain) before the t-loop.  The post-barrier
// dead window (ds_read + MFMA chain, ~700cy, zero VALU available — the
// recurrence forbids deferring elem across the barrier) can only be filled
// by the OTHER block's elem burst; phase offset is neutrally stable, so a
// one-time stagger should persist across all 128 steps.
// Structure: 512 thr / 8 waves, BT=16, grid 512, 1 barrier/step, x prefetch,
// hw exp2 (R8: hw trans ~13-16cy < 22cy poly), MFMA cluster + setprio (R9).
// Wave wv owns h in [8wv,8wv+8) as 2 gate-interleaved row-tiles:
//   D element r of lane (bl,kg) = gate r of h = hbase+kg (all 4 gates/lane).
// log2e folded into weights (i,f,o x1.4427; g x2.8854); merged-rcp gate math:
//   5 exp2 + 2 rcp = 7 trans/element.

#define TT  128
#define DIN 32
#define BT  16
#define L2E 1.44269504088896340736f

typedef _Float16 h8 __attribute__((ext_vector_type(8)));
typedef __fp16   p2 __attribute__((ext_vector_type(2)));
typedef float    f4 __attribute__((ext_vector_type(4)));

#define MFMA(A, B, C) __builtin_amdgcn_mfma_f32_16x16x32_f16((A), (B), (C), 0, 0, 0)

__device__ __forceinline__ h8 cvt8s(const float* p, float s) {
    float4 a = *(const float4*)p;
    float4 b = *(const float4*)(p + 4);
    union { h8 v; p2 q[4]; } u;
    u.q[0] = __builtin_amdgcn_cvt_pkrtz(a.x * s, a.y * s);
    u.q[1] = __builtin_amdgcn_cvt_pkrtz(a.z * s, a.w * s);
    u.q[2] = __builtin_amdgcn_cvt_pkrtz(b.x * s, b.y * s);
    u.q[3] = __builtin_amdgcn_cvt_pkrtz(b.z * s, b.w * s);
    return u.v;
}

__device__ __forceinline__ h8 pack8(const float4& a, const float4& b) {
    union { h8 v; p2 q[4]; } u;
    u.q[0] = __builtin_amdgcn_cvt_pkrtz(a.x, a.y);
    u.q[1] = __builtin_amdgcn_cvt_pkrtz(a.z, a.w);
    u.q[2] = __builtin_amdgcn_cvt_pkrtz(b.x, b.y);
    u.q[3] = __builtin_amdgcn_cvt_pkrtz(b.z, b.w);
    return u.v;
}

// acc = {yi', yf', yg'(2x-scaled), yo'} (log2e pre-folded); updates c, returns h.
__device__ __forceinline__ float elem(const f4& acc, float& c) {
    float Ei = __builtin_amdgcn_exp2f(-acc[0]);
    float Ef = __builtin_amdgcn_exp2f(-acc[1]);
    float Eg = __builtin_amdgcn_exp2f(-acc[2]);
    float Eo = __builtin_amdgcn_exp2f(-acc[3]);
    float a = 1.f + Ei, b = 1.f + Eg, d = 1.f + Ef;
    float P = a * b;
    float N = c * P + (1.f - Eg) * d;
    c = N * __builtin_amdgcn_rcpf(P * d);
    float Ec = __builtin_amdgcn_exp2f(-2.f * L2E * c);
    return (1.f - Ec) * __builtin_amdgcn_rcpf((1.f + Ec) * (1.f + Eo));
}

__global__ __launch_bounds__(512, 4)
void lstm2_fused(const float* __restrict__ x,
                 const float* __restrict__ wih0, const float* __restrict__ whh0,
                 const float* __restrict__ bih0, const float* __restrict__ bhh0,
                 const float* __restrict__ wih1, const float* __restrict__ whh1,
                 const float* __restrict__ bih1, const float* __restrict__ bhh1,
                 const float* __restrict__ fcw,  const float* __restrict__ fcb,
                 float* __restrict__ out)
{
    const int tid  = threadIdx.x;
    const int lane = tid & 63;
    const int wv   = tid >> 6;      // 0..7 -> h block 8*wv
    const int bl   = lane & 15;
    const int kg   = lane >> 4;

    // ---- anti-phase stagger: odd blocks burn ~1700cy before everything ----
    if (blockIdx.x & 1) {
        float z = (float)(lane + 1);
        #pragma unroll
        for (int i = 0; i < 64; ++i) z = __builtin_amdgcn_rcpf(z + 1.0f);
        asm volatile("" :: "v"(z));   // keep the chain alive (rule #17)
    }

    __shared__ alignas(16) unsigned short hb[2][2][BT * 64];  // layer,parity,[b][h] f16
    __shared__ float wpart[8][BT];

    for (int i = tid; i < (int)(sizeof(hb) / 4); i += 512) ((int*)hb)[i] = 0;

    // ---- weights: gate-interleaved row tiles, log2e folded ----
    h8 W0[2][3], W1[2][4];
    f4 b0v[2], b1v[2];
    #pragma unroll
    for (int t = 0; t < 2; ++t) {
        const int hbse = 8 * wv + 4 * t;
        const int gam  = bl & 3;                         // gate of this A-row
        const int g    = 64 * gam + hbse + (bl >> 2);    // global weight row
        const float sc = (gam == 2) ? 2.f * L2E : L2E;
        W0[t][0] = cvt8s(wih0 + g * 32 + 8 * kg, sc);
        W0[t][1] = cvt8s(whh0 + g * 64 + 8 * kg, sc);
        W0[t][2] = cvt8s(whh0 + g * 64 + 32 + 8 * kg, sc);
        W1[t][0] = cvt8s(wih1 + g * 64 + 8 * kg, sc);
        W1[t][1] = cvt8s(wih1 + g * 64 + 32 + 8 * kg, sc);
        W1[t][2] = cvt8s(whh1 + g * 64 + 8 * kg, sc);
        W1[t][3] = cvt8s(whh1 + g * 64 + 32 + 8 * kg, sc);
        #pragma unroll
        for (int r = 0; r < 4; ++r) {
            const int gr = 64 * r + hbse + kg;           // D element r = gate r of h=hbse+kg
            const float scr = (r == 2) ? 2.f * L2E : L2E;
            b0v[t][r] = (bih0[gr] + bhh0[gr]) * scr;
            b1v[t][r] = (bih1[gr] + bhh1[gr]) * scr;
        }
    }

    const int bbase = blockIdx.x * BT;
    const float* xp = x + (size_t)(bbase + bl) * (TT * DIN) + 8 * kg;

    float c0[2] = {0.f, 0.f}, c1[2] = {0.f, 0.f}, h1f[2] = {0.f, 0.f};

    __syncthreads();   // LDS zero visible

    const int swz = (bl & 7) << 4;
    char* lb = (char*)hb;
    const int rowoff = bl * 128;
    const int rd0 = rowoff + ((16 * kg) ^ swz);
    const int rd1 = rowoff + ((64 + 16 * kg) ^ swz);
    const int wro0 = rowoff + ((16 * wv + 2 * kg) ^ swz);        // h = 8wv+kg   (t=0)
    const int wro1 = rowoff + ((16 * wv + 8 + 2 * kg) ^ swz);    // h = 8wv+4+kg (t=1)

    h8 xcur;

    // One skewed step: {L0[it], L1[it-1]} with MFMA cluster first, then elems.
    auto STEP = [&](int wp, int rp, const float* xnext) {
        float4 xnA, xnB;
        if (xnext) { xnA = *(const float4*)xnext; xnB = *(const float4*)(xnext + 4); }

        h8 hr0 = *(const h8*)(lb + rp * 2048 + rd0);          // h0[it-1]
        h8 hr1 = *(const h8*)(lb + rp * 2048 + rd1);
        h8 g1a = *(const h8*)(lb + 4096 + rp * 2048 + rd0);   // h1[it-2]
        h8 g1b = *(const h8*)(lb + 4096 + rp * 2048 + rd1);

        __builtin_amdgcn_s_setprio(1);
        f4 a00 = b0v[0];
        a00 = MFMA(W0[0][1], hr0, a00);
        a00 = MFMA(W0[0][2], hr1, a00);
        a00 = MFMA(W0[0][0], xcur, a00);
        f4 a01 = b0v[1];
        a01 = MFMA(W0[1][1], hr0, a01);
        a01 = MFMA(W0[1][2], hr1, a01);
        a01 = MFMA(W0[1][0], xcur, a01);
        f4 a10 = b1v[0];
        a10 = MFMA(W1[0][0], hr0, a10);
        a10 = MFMA(W1[0][1], hr1, a10);
        a10 = MFMA(W1[0][2], g1a, a10);
        a10 = MFMA(W1[0][3], g1b, a10);
        f4 a11 = b1v[1];
        a11 = MFMA(W1[1][0], hr0, a11);
        a11 = MFMA(W1[1][1], hr1, a11);
        a11 = MFMA(W1[1][2], g1a, a11);
        a11 = MFMA(W1[1][3], g1b, a11);
        __builtin_amdgcn_s_setprio(0);

        float h00 = elem(a00, c0[0]);
        float h01 = elem(a01, c0[1]);
        float h10 = elem(a10, c1[0]);
        float h11 = elem(a11, c1[1]);
        h1f[0] = h10; h1f[1] = h11;

        *(_Float16*)(lb + wp * 2048 + wro0) = (_Float16)h00;
        *(_Float16*)(lb + wp * 2048 + wro1) = (_Float16)h01;
        *(_Float16*)(lb + 4096 + wp * 2048 + wro0) = (_Float16)h10;
        *(_Float16*)(lb + 4096 + wp * 2048 + wro1) = (_Float16)h11;

        if (xnext) xcur = pack8(xnA, xnB);
        __syncthreads();
    };

    // ---- it = 0: L0 only (t=0); h0[-1]=0 from zeroed parity-1 buffer ----
    {
        float4 x0a = *(const float4*)(xp);
        float4 x0b = *(const float4*)(xp + 4);
        float4 xnA = *(const float4*)(xp + DIN);       // prefetch x[1]
        float4 xnB = *(const float4*)(xp + DIN + 4);
        h8 xc  = pack8(x0a, x0b);
        h8 hr0 = *(const h8*)(lb + 2048 + rd0);
        h8 hr1 = *(const h8*)(lb + 2048 + rd1);
        __builtin_amdgcn_s_setprio(1);
        f4 a00 = b0v[0];
        a00 = MFMA(W0[0][1], hr0, a00);
        a00 = MFMA(W0[0][2], hr1, a00);
        a00 = MFMA(W0[0][0], xc, a00);
        f4 a01 = b0v[1];
        a01 = MFMA(W0[1][1], hr0, a01);
        a01 = MFMA(W0[1][2], hr1, a01);
        a01 = MFMA(W0[1][0], xc, a01);
        __builtin_amdgcn_s_setprio(0);
        float h00 = elem(a00, c0[0]);
        float h01 = elem(a01, c0[1]);
        *(_Float16*)(lb + 0 * 2048 + wro0) = (_Float16)h00;
        *(_Float16*)(lb + 0 * 2048 + wro1) = (_Float16)h01;
        xcur = pack8(xnA, xnB);
        __syncthreads();
    }

    // ---- it = 1..126 unrolled x2 (parities literal), then peel it=127 ----
    for (int itp = 1; itp < TT - 1; itp += 2) {
        STEP(1, 0, xp + (itp + 1) * DIN);   // it = itp   (odd)
        STEP(0, 1, xp + (itp + 2) * DIN);   // it = itp+1 (even)
    }
    STEP(1, 0, nullptr);                    // it = 127

    // ---- tail: L1 for t = TT-1 (reads parity 1) ----
    {
        h8 hr0 = *(const h8*)(lb + 2048 + rd0);              // h0[127]
        h8 hr1 = *(const h8*)(lb + 2048 + rd1);
        h8 g1a = *(const h8*)(lb + 4096 + 2048 + rd0);       // h1[126]
        h8 g1b = *(const h8*)(lb + 4096 + 2048 + rd1);
        #pragma unroll
        for (int t = 0; t < 2; ++t) {
            f4 acc = b1v[t];
            acc = MFMA(W1[t][0], hr0, acc);
            acc = MFMA(W1[t][1], hr1, acc);
            acc = MFMA(W1[t][2], g1a, acc);
            acc = MFMA(W1[t][3], g1b, acc);
            h1f[t] = elem(acc, c1[t]);
        }
    }

    // ---- head: out[b] = h1 . fc_w + fc_b ----
    float part = h1f[0] * fcw[8 * wv + kg] + h1f[1] * fcw[8 * wv + 4 + kg];
    part += __shfl_xor(part, 16, 64);
    part += __shfl_xor(part, 32, 64);
    if (lane < 16) wpart[wv][lane] = part;
    __syncthreads();
    if (tid < BT) {
        float s = fcb[0];
        #pragma unroll
        for (int w = 0; w < 8; ++w) s += wpart[w][tid];
        out[bbase + tid] = s;
    }
}

extern "C" void kernel_launch(void* const* d_in, const int* in_sizes, int n_in,
                              void* d_out, int out_size, void* d_ws, size_t ws_size,
                              hipStream_t stream) {
    (void)in_sizes; (void)n_in; (void)d_ws; (void)ws_size; (void)out_size;
    lstm2_fused<<<dim3(8192 / BT), dim3(512), 0, stream>>>(
        (const float*)d_in[0],
        (const float*)d_in[1], (const float*)d_in[2],
        (const float*)d_in[3], (const float*)d_in[4],
        (const float*)d_in[5], (const float*)d_in[6],
        (const float*)d_in[7], (const float*)d_in[8],
        (const float*)d_in[9], (const float*)d_in[10],
        (float*)d_out);
}

// Round 11
// 183.071 us; speedup vs baseline: 1.0125x; 1.0125x over previous
//
#include <hip/hip_runtime.h>

// 2-layer fused LSTM + linear head.  B=8192, T=128, D=32, H=64, gates=256.
// R11: ONE barrier domain per CU.  1024 thr / 16 waves, BT=32 (two batch-16
// halves), grid 256 -> 1 block/CU, 4 waves/SIMD (same as R4/R9).  Per-wave
// code identical to R9 (14 MFMA cluster + setprio, 4 elems/lane, 64 VGPR):
// wave wv -> batch-half bh=wv>>3, h-block hw=wv&7 (h in [8hw,8hw+8)).
// Tests the hypothesis that the 2 independent phase-locked 8-wave barrier
// domains/CU (R4..R10, ~1400cy/step unmodeled overhead) serialize their
// window overheads; merging them should reclaim up to one overhead/step.
// log2e folded into weights (i,f,o x1.4427; g x2.8854); merged-rcp gate math:
//   5 exp2 + 2 rcp = 7 trans/element (hw trans: R8 proved poly is worse).

#define TT  128
#define DIN 32
#define BT  32
#define L2E 1.44269504088896340736f

typedef _Float16 h8 __attribute__((ext_vector_type(8)));
typedef __fp16   p2 __attribute__((ext_vector_type(2)));
typedef float    f4 __attribute__((ext_vector_type(4)));

#define MFMA(A, B, C) __builtin_amdgcn_mfma_f32_16x16x32_f16((A), (B), (C), 0, 0, 0)

__device__ __forceinline__ h8 cvt8s(const float* p, float s) {
    float4 a = *(const float4*)p;
    float4 b = *(const float4*)(p + 4);
    union { h8 v; p2 q[4]; } u;
    u.q[0] = __builtin_amdgcn_cvt_pkrtz(a.x * s, a.y * s);
    u.q[1] = __builtin_amdgcn_cvt_pkrtz(a.z * s, a.w * s);
    u.q[2] = __builtin_amdgcn_cvt_pkrtz(b.x * s, b.y * s);
    u.q[3] = __builtin_amdgcn_cvt_pkrtz(b.z * s, b.w * s);
    return u.v;
}

__device__ __forceinline__ h8 pack8(const float4& a, const float4& b) {
    union { h8 v; p2 q[4]; } u;
    u.q[0] = __builtin_amdgcn_cvt_pkrtz(a.x, a.y);
    u.q[1] = __builtin_amdgcn_cvt_pkrtz(a.z, a.w);
    u.q[2] = __builtin_amdgcn_cvt_pkrtz(b.x, b.y);
    u.q[3] = __builtin_amdgcn_cvt_pkrtz(b.z, b.w);
    return u.v;
}

// acc = {yi', yf', yg'(2x-scaled), yo'} (log2e pre-folded); updates c, returns h.
__device__ __forceinline__ float elem(const f4& acc, float& c) {
    float Ei = __builtin_amdgcn_exp2f(-acc[0]);
    float Ef = __builtin_amdgcn_exp2f(-acc[1]);
    float Eg = __builtin_amdgcn_exp2f(-acc[2]);
    float Eo = __builtin_amdgcn_exp2f(-acc[3]);
    float a = 1.f + Ei, b = 1.f + Eg, d = 1.f + Ef;
    float P = a * b;
    float N = c * P + (1.f - Eg) * d;
    c = N * __builtin_amdgcn_rcpf(P * d);
    float Ec = __builtin_amdgcn_exp2f(-2.f * L2E * c);
    return (1.f - Ec) * __builtin_amdgcn_rcpf((1.f + Ec) * (1.f + Eo));
}

__global__ __launch_bounds__(1024, 4)
void lstm2_fused(const float* __restrict__ x,
                 const float* __restrict__ wih0, const float* __restrict__ whh0,
                 const float* __restrict__ bih0, const float* __restrict__ bhh0,
                 const float* __restrict__ wih1, const float* __restrict__ whh1,
                 const float* __restrict__ bih1, const float* __restrict__ bhh1,
                 const float* __restrict__ fcw,  const float* __restrict__ fcb,
                 float* __restrict__ out)
{
    const int tid  = threadIdx.x;
    const int lane = tid & 63;
    const int wv   = tid >> 6;      // 0..15
    const int hw   = wv & 7;        // h block 8*hw
    const int bh   = wv >> 3;       // batch half 0/1
    const int bl   = lane & 15;
    const int kg   = lane >> 4;

    // [layer][parity][b (32 rows)][h (64)] f16, XOR-swizzled; 16 KB
    __shared__ alignas(16) unsigned short hb[2][2][BT * 64];
    __shared__ float wpart[16][16];

    for (int i = tid; i < (int)(sizeof(hb) / 4); i += 1024) ((int*)hb)[i] = 0;

    // ---- weights: gate-interleaved row tiles, log2e folded ----
    h8 W0[2][3], W1[2][4];
    f4 b0v[2], b1v[2];
    #pragma unroll
    for (int t = 0; t < 2; ++t) {
        const int hbse = 8 * hw + 4 * t;
        const int gam  = bl & 3;                         // gate of this A-row
        const int g    = 64 * gam + hbse + (bl >> 2);    // global weight row
        const float sc = (gam == 2) ? 2.f * L2E : L2E;
        W0[t][0] = cvt8s(wih0 + g * 32 + 8 * kg, sc);
        W0[t][1] = cvt8s(whh0 + g * 64 + 8 * kg, sc);
        W0[t][2] = cvt8s(whh0 + g * 64 + 32 + 8 * kg, sc);
        W1[t][0] = cvt8s(wih1 + g * 64 + 8 * kg, sc);
        W1[t][1] = cvt8s(wih1 + g * 64 + 32 + 8 * kg, sc);
        W1[t][2] = cvt8s(whh1 + g * 64 + 8 * kg, sc);
        W1[t][3] = cvt8s(whh1 + g * 64 + 32 + 8 * kg, sc);
        #pragma unroll
        for (int r = 0; r < 4; ++r) {
            const int gr = 64 * r + hbse + kg;           // D element r = gate r of h=hbse+kg
            const float scr = (r == 2) ? 2.f * L2E : L2E;
            b0v[t][r] = (bih0[gr] + bhh0[gr]) * scr;
            b1v[t][r] = (bih1[gr] + bhh1[gr]) * scr;
        }
    }

    const int bbase = blockIdx.x * BT;
    const int brow  = 16 * bh + bl;                      // batch row within block
    const float* xp = x + (size_t)(bbase + brow) * (TT * DIN) + 8 * kg;

    float c0[2] = {0.f, 0.f}, c1[2] = {0.f, 0.f}, h1f[2] = {0.f, 0.f};

    __syncthreads();   // LDS zero visible

    const int swz = (brow & 7) << 4;
    char* lb = (char*)hb;
    const int rowoff = brow * 128;
    const int rd0 = rowoff + ((16 * kg) ^ swz);
    const int rd1 = rowoff + ((64 + 16 * kg) ^ swz);
    const int wro0 = rowoff + ((16 * hw + 2 * kg) ^ swz);        // h = 8hw+kg   (t=0)
    const int wro1 = rowoff + ((16 * hw + 8 + 2 * kg) ^ swz);    // h = 8hw+4+kg (t=1)

    h8 xcur;

    // One skewed step: {L0[it], L1[it-1]}; MFMA cluster first, then elems.
    // Parity regions are 4096 B now (2 parity x 32 rows x 128 B per layer).
    auto STEP = [&](int wp, int rp, const float* xnext) {
        float4 xnA, xnB;
        if (xnext) { xnA = *(const float4*)xnext; xnB = *(const float4*)(xnext + 4); }

        h8 hr0 = *(const h8*)(lb + rp * 4096 + rd0);          // h0[it-1]
        h8 hr1 = *(const h8*)(lb + rp * 4096 + rd1);
        h8 g1a = *(const h8*)(lb + 8192 + rp * 4096 + rd0);   // h1[it-2]
        h8 g1b = *(const h8*)(lb + 8192 + rp * 4096 + rd1);

        __builtin_amdgcn_s_setprio(1);
        f4 a00 = b0v[0];
        a00 = MFMA(W0[0][1], hr0, a00);
        a00 = MFMA(W0[0][2], hr1, a00);
        a00 = MFMA(W0[0][0], xcur, a00);
        f4 a01 = b0v[1];
        a01 = MFMA(W0[1][1], hr0, a01);
        a01 = MFMA(W0[1][2], hr1, a01);
        a01 = MFMA(W0[1][0], xcur, a01);
        f4 a10 = b1v[0];
        a10 = MFMA(W1[0][0], hr0, a10);
        a10 = MFMA(W1[0][1], hr1, a10);
        a10 = MFMA(W1[0][2], g1a, a10);
        a10 = MFMA(W1[0][3], g1b, a10);
        f4 a11 = b1v[1];
        a11 = MFMA(W1[1][0], hr0, a11);
        a11 = MFMA(W1[1][1], hr1, a11);
        a11 = MFMA(W1[1][2], g1a, a11);
        a11 = MFMA(W1[1][3], g1b, a11);
        __builtin_amdgcn_s_setprio(0);

        float h00 = elem(a00, c0[0]);
        float h01 = elem(a01, c0[1]);
        float h10 = elem(a10, c1[0]);
        float h11 = elem(a11, c1[1]);
        h1f[0] = h10; h1f[1] = h11;

        *(_Float16*)(lb + wp * 4096 + wro0) = (_Float16)h00;
        *(_Float16*)(lb + wp * 4096 + wro1) = (_Float16)h01;
        *(_Float16*)(lb + 8192 + wp * 4096 + wro0) = (_Float16)h10;
        *(_Float16*)(lb + 8192 + wp * 4096 + wro1) = (_Float16)h11;

        if (xnext) xcur = pack8(xnA, xnB);
        __syncthreads();
    };

    // ---- it = 0: L0 only (t=0); h0[-1]=0 from zeroed parity-1 buffer ----
    {
        float4 x0a = *(const float4*)(xp);
        float4 x0b = *(const float4*)(xp + 4);
        float4 xnA = *(const float4*)(xp + DIN);       // prefetch x[1]
        float4 xnB = *(const float4*)(xp + DIN + 4);
        h8 xc  = pack8(x0a, x0b);
        h8 hr0 = *(const h8*)(lb + 4096 + rd0);
        h8 hr1 = *(const h8*)(lb + 4096 + rd1);
        __builtin_amdgcn_s_setprio(1);
        f4 a00 = b0v[0];
        a00 = MFMA(W0[0][1], hr0, a00);
        a00 = MFMA(W0[0][2], hr1, a00);
        a00 = MFMA(W0[0][0], xc, a00);
        f4 a01 = b0v[1];
        a01 = MFMA(W0[1][1], hr0, a01);
        a01 = MFMA(W0[1][2], hr1, a01);
        a01 = MFMA(W0[1][0], xc, a01);
        __builtin_amdgcn_s_setprio(0);
        float h00 = elem(a00, c0[0]);
        float h01 = elem(a01, c0[1]);
        *(_Float16*)(lb + 0 * 4096 + wro0) = (_Float16)h00;
        *(_Float16*)(lb + 0 * 4096 + wro1) = (_Float16)h01;
        xcur = pack8(xnA, xnB);
        __syncthreads();
    }

    // ---- it = 1..126 unrolled x2 (parities literal), then peel it=127 ----
    for (int itp = 1; itp < TT - 1; itp += 2) {
        STEP(1, 0, xp + (itp + 1) * DIN);   // it = itp   (odd)
        STEP(0, 1, xp + (itp + 2) * DIN);   // it = itp+1 (even)
    }
    STEP(1, 0, nullptr);                    // it = 127

    // ---- tail: L1 for t = TT-1 (reads parity 1) ----
    {
        h8 hr0 = *(const h8*)(lb + 4096 + rd0);              // h0[127]
        h8 hr1 = *(const h8*)(lb + 4096 + rd1);
        h8 g1a = *(const h8*)(lb + 8192 + 4096 + rd0);       // h1[126]
        h8 g1b = *(const h8*)(lb + 8192 + 4096 + rd1);
        #pragma unroll
        for (int t = 0; t < 2; ++t) {
            f4 acc = b1v[t];
            acc = MFMA(W1[t][0], hr0, acc);
            acc = MFMA(W1[t][1], hr1, acc);
            acc = MFMA(W1[t][2], g1a, acc);
            acc = MFMA(W1[t][3], g1b, acc);
            h1f[t] = elem(acc, c1[t]);
        }
    }

    // ---- head: out[b] = h1 . fc_w + fc_b ----
    float part = h1f[0] * fcw[8 * hw + kg] + h1f[1] * fcw[8 * hw + 4 + kg];
    part += __shfl_xor(part, 16, 64);
    part += __shfl_xor(part, 32, 64);
    if (lane < 16) wpart[wv][lane] = part;
    __syncthreads();
    if (tid < BT) {
        const int tbh = tid >> 4, tbl = tid & 15;
        float s = fcb[0];
        #pragma unroll
        for (int w = 0; w < 8; ++w) s += wpart[8 * tbh + w][tbl];
        out[bbase + tid] = s;
    }
}

extern "C" void kernel_launch(void* const* d_in, const int* in_sizes, int n_in,
                              void* d_out, int out_size, void* d_ws, size_t ws_size,
                              hipStream_t stream) {
    (void)in_sizes; (void)n_in; (void)d_ws; (void)ws_size; (void)out_size;
    lstm2_fused<<<dim3(8192 / BT), dim3(1024), 0, stream>>>(
        (const float*)d_in[0],
        (const float*)d_in[1], (const float*)d_in[2],
        (const float*)d_in[3], (const float*)d_in[4],
        (const float*)d_in[5], (const float*)d_in[6],
        (const float*)d_in[7], (const float*)d_in[8],
        (const float*)d_in[9], (const float*)d_in[10],
        (float*)d_out);
}